// Round 5
// baseline (482.047 us; speedup 1.0000x reference)
//
#include <hip/hip_runtime.h>
#include <hip/hip_bf16.h>
#include <cstdint>

#define N_FEATS_IN 256
#define HID 128
#define OUTF 64
#define SITEMS 8  // elements per thread in hierarchical scan; 256*8=2048/block
#define NXCD 8

typedef __bf16 bf16x8 __attribute__((ext_vector_type(8)));
typedef __bf16 bf16x2 __attribute__((ext_vector_type(2)));
typedef float f32x4 __attribute__((ext_vector_type(4)));

__device__ __forceinline__ int xcc_id() {
  int x;
  asm volatile("s_getreg_b32 %0, hwreg(HW_REG_XCC_ID, 0, 32)" : "=s"(x));
  return x & (NXCD - 1);
}

// ---- CSR build ----------------------------------------------------------
// XCD-private histograms: atomics stay in the local L2 (workgroup scope);
// slice x is only ever touched by workgroups physically on XCD x.

__global__ __launch_bounds__(256) void count_deg_kernel(const int* __restrict__ ei, int E,
    int N, int* __restrict__ cnt8, int* __restrict__ erank) {
  int e = blockIdx.x * 256 + threadIdx.x;
  int x = xcc_id();
  if (e < E) {
    int c = ei[E + e];  // target
    int lr = __hip_atomic_fetch_add(&cnt8[(size_t)x * N + c], 1,
                                    __ATOMIC_RELAXED, __HIP_MEMORY_SCOPE_WORKGROUP);
    erank[e] = lr | (x << 28);
  }
}

// deg[c] = sum over slices; cnt8[x][c] becomes the per-XCD exclusive offset
__global__ __launch_bounds__(256) void combine_kernel(int* __restrict__ cnt8,
                                                      int* __restrict__ deg, int n) {
  int c = blockIdx.x * 256 + threadIdx.x;
  if (c < n) {
    int s = 0;
#pragma unroll
    for (int x = 0; x < NXCD; ++x) {
      int v = cnt8[(size_t)x * n + c];
      cnt8[(size_t)x * n + c] = s;
      s += v;
    }
    deg[c] = s;
  }
}

__global__ __launch_bounds__(256) void dinv_kernel(const int* __restrict__ deg,
                                                   float* __restrict__ dinv, int n) {
  int i = blockIdx.x * 256 + threadIdx.x;
  if (i < n) dinv[i] = rsqrtf((float)(deg[i] + 1));  // +1 self-loop
}

// ---- hierarchical exclusive scan: ptr[0..n], ptr[n] = total -------------

__global__ __launch_bounds__(256) void scan_part_kernel(const int* __restrict__ cnt, int n,
                                                        int* __restrict__ bsum) {
  __shared__ int ts[256];
  const int t = threadIdx.x;
  int base = (blockIdx.x * 256 + t) * SITEMS;
  int s = 0;
#pragma unroll
  for (int i = 0; i < SITEMS; ++i) {
    int idx = base + i;
    if (idx < n) s += cnt[idx];
  }
  ts[t] = s;
  __syncthreads();
  for (int off = 128; off > 0; off >>= 1) {
    if (t < off) ts[t] += ts[t + off];
    __syncthreads();
  }
  if (t == 0) bsum[blockIdx.x] = ts[0];
}

__global__ __launch_bounds__(256) void scan_bsum_kernel(int* __restrict__ bsum, int nb) {
  __shared__ int ts[256];
  const int t = threadIdx.x;
  int v = (t < nb) ? bsum[t] : 0;
  ts[t] = v;
  __syncthreads();
  for (int off = 1; off < 256; off <<= 1) {
    int u = (t >= off) ? ts[t - off] : 0;
    __syncthreads();
    ts[t] += u;
    __syncthreads();
  }
  if (t < nb) bsum[t] = ts[t] - v;  // exclusive
}

__global__ __launch_bounds__(256) void scan_final_kernel(const int* __restrict__ cnt, int n,
    const int* __restrict__ bsum, int* __restrict__ ptr) {
  __shared__ int ts[256];
  const int t = threadIdx.x;
  int base = (blockIdx.x * 256 + t) * SITEMS;
  int loc[SITEMS];
  int s = 0;
#pragma unroll
  for (int i = 0; i < SITEMS; ++i) {
    int idx = base + i;
    loc[i] = (idx < n) ? cnt[idx] : 0;
    s += loc[i];
  }
  ts[t] = s;
  __syncthreads();
  for (int off = 1; off < 256; off <<= 1) {
    int u = (t >= off) ? ts[t - off] : 0;
    __syncthreads();
    ts[t] += u;
    __syncthreads();
  }
  int run = bsum[blockIdx.x] + ts[t] - s;  // exclusive prefix for this thread
#pragma unroll
  for (int i = 0; i < SITEMS; ++i) {
    int idx = base + i;
    if (idx < n) ptr[idx] = run;
    run += loc[i];
  }
  if (base < n && base + SITEMS >= n) ptr[n] = run;  // thread covering n-1
}

// no atomic: pos = ptr[c] + offs[xcd][c] + local_rank; one 8B store per edge

__global__ __launch_bounds__(256) void fill_kernel(const int* __restrict__ ei, int E, int N,
    const int* __restrict__ ptr, const int* __restrict__ offs, const int* __restrict__ erank,
    const float* __restrict__ dinv, int2* __restrict__ erec) {
  int e = blockIdx.x * 256 + threadIdx.x;
  if (e < E) {
    int r = ei[e];       // source
    int c = ei[E + e];   // target
    int er = erank[e];
    int x = er >> 28;
    int lr = er & 0x0FFFFFFF;
    int pos = ptr[c] + offs[(size_t)x * N + c] + lr;
    int2 rec;
    rec.x = r;
    rec.y = __float_as_int(dinv[r] * dinv[c]);
    erec[pos] = rec;
  }
}

// ---- weight repack into MFMA B-fragment order ---------------------------
// B-frag for mfma_f32_16x16x32_bf16: lane l holds B[k = (l>>4)*8 + j][n = l&15]

__global__ __launch_bounds__(256) void pack_w1_kernel(const float* __restrict__ W,
                                                      __bf16* __restrict__ Wp) {
  int idx = blockIdx.x * 256 + threadIdx.x;  // 8s * 8t * 64l * 8j = 32768
  if (idx >= 32768) return;
  int j = idx & 7, l = (idx >> 3) & 63, t = (idx >> 9) & 7, s = idx >> 12;
  int k = s * 32 + (l >> 4) * 8 + j;
  int n = t * 16 + (l & 15);
  Wp[idx] = (__bf16)W[k * HID + n];
}

__global__ __launch_bounds__(256) void pack_wc_kernel(const float* __restrict__ Wmu,
    const float* __restrict__ Wlv, __bf16* __restrict__ Wp) {
  int idx = blockIdx.x * 256 + threadIdx.x;  // 4s * 8t * 64l * 8j = 16384
  if (idx >= 16384) return;
  int j = idx & 7, l = (idx >> 3) & 63, t = (idx >> 9) & 7, s = idx >> 12;
  int k = s * 32 + (l >> 4) * 8 + j;
  int g = t * 16 + (l & 15);
  float v = (g < OUTF) ? Wmu[k * OUTF + g] : Wlv[k * OUTF + (g - OUTF)];
  Wp[idx] = (__bf16)v;
}

// ---- GEMM1 (MFMA): Yb[N][128] = bf16( X[N][256] @ W1 ) ------------------

__global__ __launch_bounds__(256) void gemm1_mfma(const float* __restrict__ X,
    const __bf16* __restrict__ Wp, __bf16* __restrict__ Yb, int nrows) {
  const int lane = threadIdx.x & 63;
  const int wave = threadIdx.x >> 6;
  const int rb = blockIdx.x * 128 + wave * 32;
  const int lm = lane & 15;
  const int q = lane >> 4;

  f32x4 acc[2][8];
#pragma unroll
  for (int m = 0; m < 2; ++m)
#pragma unroll
    for (int t = 0; t < 8; ++t) acc[m][t] = (f32x4)0.f;

  int r0 = min(rb + lm, nrows - 1);
  int r1 = min(rb + 16 + lm, nrows - 1);
  const float* x0 = X + (size_t)r0 * N_FEATS_IN + q * 8;
  const float* x1 = X + (size_t)r1 * N_FEATS_IN + q * 8;
  const bf16x8* wp = (const bf16x8*)Wp;

#pragma unroll
  for (int s = 0; s < 8; ++s) {
    float4 u0 = ((const float4*)(x0 + s * 32))[0];
    float4 v0 = ((const float4*)(x0 + s * 32))[1];
    float4 u1 = ((const float4*)(x1 + s * 32))[0];
    float4 v1 = ((const float4*)(x1 + s * 32))[1];
    bf16x8 a0, a1;
    a0[0] = (__bf16)u0.x; a0[1] = (__bf16)u0.y; a0[2] = (__bf16)u0.z; a0[3] = (__bf16)u0.w;
    a0[4] = (__bf16)v0.x; a0[5] = (__bf16)v0.y; a0[6] = (__bf16)v0.z; a0[7] = (__bf16)v0.w;
    a1[0] = (__bf16)u1.x; a1[1] = (__bf16)u1.y; a1[2] = (__bf16)u1.z; a1[3] = (__bf16)u1.w;
    a1[4] = (__bf16)v1.x; a1[5] = (__bf16)v1.y; a1[6] = (__bf16)v1.z; a1[7] = (__bf16)v1.w;
#pragma unroll
    for (int t = 0; t < 8; ++t) {
      bf16x8 b = wp[(s * 8 + t) * 64 + lane];
      acc[0][t] = __builtin_amdgcn_mfma_f32_16x16x32_bf16(a0, b, acc[0][t], 0, 0, 0);
      acc[1][t] = __builtin_amdgcn_mfma_f32_16x16x32_bf16(a1, b, acc[1][t], 0, 0, 0);
    }
  }
  // D: col = lane&15, row = q*4 + reg
#pragma unroll
  for (int m = 0; m < 2; ++m) {
    int rowbase = rb + m * 16 + q * 4;
#pragma unroll
    for (int t = 0; t < 8; ++t) {
#pragma unroll
      for (int r = 0; r < 4; ++r) {
        int row = rowbase + r;
        if (row < nrows) Yb[(size_t)row * HID + t * 16 + lm] = (__bf16)acc[m][t][r];
      }
    }
  }
}

// ---- aggregation (bf16 in/out, f32 accumulate) --------------------------
// Fout[c] = dinv[c]^2*Fin[c] + sum_e norm[e]*Fin[src[e]]; 1 wave/node, 2 feats/lane

__global__ __launch_bounds__(64) void agg_kernel(const __bf16* __restrict__ Fin,
    const int* __restrict__ ptr, const int2* __restrict__ erec,
    const float* __restrict__ dinv, const float* __restrict__ bias,
    __bf16* __restrict__ Fout, int do_relu) {
  const int c = blockIdx.x;
  const int t = threadIdx.x;
  const float d = dinv[c];
  bf16x2 sv = ((const bf16x2*)(Fin + (size_t)c * HID))[t];
  float ax = d * d * (float)sv[0];
  float ay = d * d * (float)sv[1];
  const int beg = ptr[c], end = ptr[c + 1];
  int e = beg;
  for (; e + 4 <= end; e += 4) {
    int2 p0 = erec[e], p1 = erec[e + 1], p2 = erec[e + 2], p3 = erec[e + 3];
    float n0 = __int_as_float(p0.y), n1 = __int_as_float(p1.y);
    float n2 = __int_as_float(p2.y), n3 = __int_as_float(p3.y);
    bf16x2 v0 = ((const bf16x2*)(Fin + (size_t)p0.x * HID))[t];
    bf16x2 v1 = ((const bf16x2*)(Fin + (size_t)p1.x * HID))[t];
    bf16x2 v2 = ((const bf16x2*)(Fin + (size_t)p2.x * HID))[t];
    bf16x2 v3 = ((const bf16x2*)(Fin + (size_t)p3.x * HID))[t];
    ax = fmaf(n0, (float)v0[0], ax); ay = fmaf(n0, (float)v0[1], ay);
    ax = fmaf(n1, (float)v1[0], ax); ay = fmaf(n1, (float)v1[1], ay);
    ax = fmaf(n2, (float)v2[0], ax); ay = fmaf(n2, (float)v2[1], ay);
    ax = fmaf(n3, (float)v3[0], ax); ay = fmaf(n3, (float)v3[1], ay);
  }
  for (; e < end; ++e) {
    int2 p = erec[e];
    float nn = __int_as_float(p.y);
    bf16x2 v = ((const bf16x2*)(Fin + (size_t)p.x * HID))[t];
    ax = fmaf(nn, (float)v[0], ax);
    ay = fmaf(nn, (float)v[1], ay);
  }
  if (do_relu) {
    ax = fmaxf(ax + bias[2 * t], 0.f);
    ay = fmaxf(ay + bias[2 * t + 1], 0.f);
  }
  bf16x2 o;
  o[0] = (__bf16)ax;
  o[1] = (__bf16)ay;
  ((bf16x2*)(Fout + (size_t)c * HID))[t] = o;
}

// ---- GEMM2 (MFMA): [mu|lv] = Gb[N][128] @ Wc[128][128] + bias -----------

__global__ __launch_bounds__(256) void gemm2_mfma(const __bf16* __restrict__ Gb,
    const __bf16* __restrict__ Wp, const float* __restrict__ bmu,
    const float* __restrict__ blv, float* __restrict__ out, int nrows) {
  const int lane = threadIdx.x & 63;
  const int wave = threadIdx.x >> 6;
  const int rb = blockIdx.x * 128 + wave * 32;
  const int lm = lane & 15;
  const int q = lane >> 4;

  f32x4 acc[2][8];
#pragma unroll
  for (int m = 0; m < 2; ++m)
#pragma unroll
    for (int t = 0; t < 8; ++t) acc[m][t] = (f32x4)0.f;

  int r0 = min(rb + lm, nrows - 1);
  int r1 = min(rb + 16 + lm, nrows - 1);
  const __bf16* g0 = Gb + (size_t)r0 * HID + q * 8;
  const __bf16* g1 = Gb + (size_t)r1 * HID + q * 8;
  const bf16x8* wp = (const bf16x8*)Wp;

#pragma unroll
  for (int s = 0; s < 4; ++s) {
    bf16x8 a0 = *(const bf16x8*)(g0 + s * 32);
    bf16x8 a1 = *(const bf16x8*)(g1 + s * 32);
#pragma unroll
    for (int t = 0; t < 8; ++t) {
      bf16x8 b = wp[(s * 8 + t) * 64 + lane];
      acc[0][t] = __builtin_amdgcn_mfma_f32_16x16x32_bf16(a0, b, acc[0][t], 0, 0, 0);
      acc[1][t] = __builtin_amdgcn_mfma_f32_16x16x32_bf16(a1, b, acc[1][t], 0, 0, 0);
    }
  }
#pragma unroll
  for (int m = 0; m < 2; ++m) {
    int rowbase = rb + m * 16 + q * 4;
#pragma unroll
    for (int t = 0; t < 8; ++t) {
      int g = t * 16 + lm;
      float bv = (g < OUTF) ? bmu[g] : blv[g - OUTF];
      float* ob = (g < OUTF) ? (out + g) : (out + (size_t)nrows * OUTF + (g - OUTF));
#pragma unroll
      for (int r = 0; r < 4; ++r) {
        int row = rowbase + r;
        if (row < nrows) ob[(size_t)row * OUTF] = acc[m][t][r] + bv;
      }
    }
  }
}

// ---- launch -------------------------------------------------------------

extern "C" void kernel_launch(void* const* d_in, const int* in_sizes, int n_in,
                              void* d_out, int out_size, void* d_ws, size_t ws_size,
                              hipStream_t stream) {
  const float* X   = (const float*)d_in[0];
  const int*   ei  = (const int*)d_in[1];
  const float* W1  = (const float*)d_in[2];
  const float* b1  = (const float*)d_in[3];
  const float* Wmu = (const float*)d_in[4];
  const float* bmu = (const float*)d_in[5];
  const float* Wlv = (const float*)d_in[6];
  const float* blv = (const float*)d_in[7];
  float* out = (float*)d_out;

  const int N = in_sizes[0] / N_FEATS_IN;   // 100000
  const int E = in_sizes[1] / 2;            // 1600000

  char* ws = (char*)d_ws;
  size_t off = 0;
  auto alloc = [&](size_t bytes) -> void* {
    void* p = ws + off;
    off += (bytes + 255) & ~(size_t)255;
    return p;
  };
  __bf16* Yb  = (__bf16*)alloc((size_t)N * HID * 2);  // gemm1 out; reused as G
  __bf16* Hb  = (__bf16*)alloc((size_t)N * HID * 2);  // relu(Â Y + b1)
  float* dinv = (float*)alloc((size_t)N * 4);
  int*   deg  = (int*)alloc((size_t)N * 4);
  int*   ptr  = (int*)alloc((size_t)(N + 1) * 4);
  int*   cnt8 = (int*)alloc((size_t)NXCD * N * 4);  // per-XCD histogram -> offsets
  int*   erank = (int*)alloc((size_t)E * 4);
  int2*  erec = (int2*)alloc((size_t)E * 8);
  __bf16* W1p = (__bf16*)alloc(32768 * 2);
  __bf16* Wcp = (__bf16*)alloc(16384 * 2);
  int*   bsum = (int*)alloc(256 * 4);
  (void)ws_size; (void)n_in; (void)out_size;

  hipMemsetAsync(cnt8, 0, (size_t)NXCD * N * 4, stream);

  int ge = (E + 255) / 256;
  int gn = (N + 255) / 256;
  int nb = (N + 256 * SITEMS - 1) / (256 * SITEMS);  // 49 blocks for N=100000
  count_deg_kernel<<<ge, 256, 0, stream>>>(ei, E, N, cnt8, erank);
  combine_kernel<<<gn, 256, 0, stream>>>(cnt8, deg, N);
  dinv_kernel<<<gn, 256, 0, stream>>>(deg, dinv, N);
  scan_part_kernel<<<nb, 256, 0, stream>>>(deg, N, bsum);
  scan_bsum_kernel<<<1, 256, 0, stream>>>(bsum, nb);
  scan_final_kernel<<<nb, 256, 0, stream>>>(deg, N, bsum, ptr);
  fill_kernel<<<ge, 256, 0, stream>>>(ei, E, N, ptr, cnt8, erank, dinv, erec);
  pack_w1_kernel<<<128, 256, 0, stream>>>(W1, W1p);
  pack_wc_kernel<<<64, 256, 0, stream>>>(Wmu, Wlv, Wcp);

  int gblk = (N + 127) / 128;
  gemm1_mfma<<<gblk, 256, 0, stream>>>(X, W1p, Yb, N);
  agg_kernel<<<N, 64, 0, stream>>>(Yb, ptr, erec, dinv, b1, Hb, 1);  // H = relu(ÂY+b1)
  agg_kernel<<<N, 64, 0, stream>>>(Hb, ptr, erec, dinv, b1, Yb, 0);  // G = ÂH
  gemm2_mfma<<<gblk, 256, 0, stream>>>(Yb, Wcp, bmu, blv, out, N);
}

// Round 6
// 469.336 us; speedup vs baseline: 1.0271x; 1.0271x over previous
//
#include <hip/hip_runtime.h>
#include <hip/hip_bf16.h>
#include <cstdint>

#define N_FEATS_IN 256
#define HID 128
#define OUTF 64
#define SITEMS 8  // elements per thread in hierarchical scan; 256*8=2048/block
#define NXCD 8

typedef __bf16 bf16x8 __attribute__((ext_vector_type(8)));
typedef __bf16 bf16x2 __attribute__((ext_vector_type(2)));
typedef float f32x4 __attribute__((ext_vector_type(4)));

__device__ __forceinline__ int xcc_id() {
  int x;
  asm volatile("s_getreg_b32 %0, hwreg(HW_REG_XCC_ID, 0, 32)" : "=s"(x));
  return x & (NXCD - 1);
}

// ---- CSR build ----------------------------------------------------------
// XCD-private histograms: atomics stay in the local L2 (workgroup scope);
// slice x is only ever touched by workgroups physically on XCD x.

__global__ __launch_bounds__(256) void count_deg_kernel(const int* __restrict__ ei, int E,
    int N, int* __restrict__ cnt8, int* __restrict__ erank) {
  int e = blockIdx.x * 256 + threadIdx.x;
  int x = xcc_id();
  if (e < E) {
    int c = ei[E + e];  // target
    int lr = __hip_atomic_fetch_add(&cnt8[(size_t)x * N + c], 1,
                                    __ATOMIC_RELAXED, __HIP_MEMORY_SCOPE_WORKGROUP);
    erank[e] = lr | (x << 28);
  }
}

// deg[c] = sum over slices; cnt8[x][c] becomes the per-XCD exclusive offset.
// dinv folded in (saves a launch).
__global__ __launch_bounds__(256) void combine_kernel(int* __restrict__ cnt8,
    int* __restrict__ deg, float* __restrict__ dinv, int n) {
  int c = blockIdx.x * 256 + threadIdx.x;
  if (c < n) {
    int s = 0;
#pragma unroll
    for (int x = 0; x < NXCD; ++x) {
      int v = cnt8[(size_t)x * n + c];
      cnt8[(size_t)x * n + c] = s;
      s += v;
    }
    deg[c] = s;
    dinv[c] = rsqrtf((float)(s + 1));  // +1 self-loop
  }
}

// ---- hierarchical exclusive scan: ptr[0..n], ptr[n] = total -------------

__global__ __launch_bounds__(256) void scan_part_kernel(const int* __restrict__ cnt, int n,
                                                        int* __restrict__ bsum) {
  __shared__ int ts[256];
  const int t = threadIdx.x;
  int base = (blockIdx.x * 256 + t) * SITEMS;
  int s = 0;
#pragma unroll
  for (int i = 0; i < SITEMS; ++i) {
    int idx = base + i;
    if (idx < n) s += cnt[idx];
  }
  ts[t] = s;
  __syncthreads();
  for (int off = 128; off > 0; off >>= 1) {
    if (t < off) ts[t] += ts[t + off];
    __syncthreads();
  }
  if (t == 0) bsum[blockIdx.x] = ts[0];
}

__global__ __launch_bounds__(256) void scan_bsum_kernel(int* __restrict__ bsum, int nb) {
  __shared__ int ts[256];
  const int t = threadIdx.x;
  int v = (t < nb) ? bsum[t] : 0;
  ts[t] = v;
  __syncthreads();
  for (int off = 1; off < 256; off <<= 1) {
    int u = (t >= off) ? ts[t - off] : 0;
    __syncthreads();
    ts[t] += u;
    __syncthreads();
  }
  if (t < nb) bsum[t] = ts[t] - v;  // exclusive
}

__global__ __launch_bounds__(256) void scan_final_kernel(const int* __restrict__ cnt, int n,
    const int* __restrict__ bsum, int* __restrict__ ptr) {
  __shared__ int ts[256];
  const int t = threadIdx.x;
  int base = (blockIdx.x * 256 + t) * SITEMS;
  int loc[SITEMS];
  int s = 0;
#pragma unroll
  for (int i = 0; i < SITEMS; ++i) {
    int idx = base + i;
    loc[i] = (idx < n) ? cnt[idx] : 0;
    s += loc[i];
  }
  ts[t] = s;
  __syncthreads();
  for (int off = 1; off < 256; off <<= 1) {
    int u = (t >= off) ? ts[t - off] : 0;
    __syncthreads();
    ts[t] += u;
    __syncthreads();
  }
  int run = bsum[blockIdx.x] + ts[t] - s;  // exclusive prefix for this thread
#pragma unroll
  for (int i = 0; i < SITEMS; ++i) {
    int idx = base + i;
    if (idx < n) ptr[idx] = run;
    run += loc[i];
  }
  if (base < n && base + SITEMS >= n) ptr[n] = run;  // thread covering n-1
}

// no atomic: pos = ptr[c] + offs[xcd][c] + local_rank; one 8B store per edge

__global__ __launch_bounds__(256) void fill_kernel(const int* __restrict__ ei, int E, int N,
    const int* __restrict__ ptr, const int* __restrict__ offs, const int* __restrict__ erank,
    const float* __restrict__ dinv, int2* __restrict__ erec) {
  int e = blockIdx.x * 256 + threadIdx.x;
  if (e < E) {
    int r = ei[e];       // source
    int c = ei[E + e];   // target
    int er = erank[e];
    int x = er >> 28;
    int lr = er & 0x0FFFFFFF;
    int pos = ptr[c] + offs[(size_t)x * N + c] + lr;
    int2 rec;
    rec.x = r;
    rec.y = __float_as_int(dinv[r] * dinv[c]);
    erec[pos] = rec;
  }
}

// ---- weight repack into MFMA B-fragment order (one kernel) --------------
// B-frag for mfma_f32_16x16x32_bf16: lane l holds B[k = (l>>4)*8 + j][n = l&15]

__global__ __launch_bounds__(256) void pack_all_kernel(const float* __restrict__ W1,
    const float* __restrict__ Wmu, const float* __restrict__ Wlv,
    __bf16* __restrict__ W1p, __bf16* __restrict__ Wcp) {
  int idx = blockIdx.x * 256 + threadIdx.x;  // 32768 + 16384 = 49152
  if (idx < 32768) {
    int j = idx & 7, l = (idx >> 3) & 63, t = (idx >> 9) & 7, s = idx >> 12;
    int k = s * 32 + (l >> 4) * 8 + j;
    int n = t * 16 + (l & 15);
    W1p[idx] = (__bf16)W1[k * HID + n];
  } else if (idx < 49152) {
    int i2 = idx - 32768;
    int j = i2 & 7, l = (i2 >> 3) & 63, t = (i2 >> 9) & 7, s = i2 >> 12;
    int k = s * 32 + (l >> 4) * 8 + j;
    int g = t * 16 + (l & 15);
    float v = (g < OUTF) ? Wmu[k * OUTF + g] : Wlv[k * OUTF + (g - OUTF)];
    Wcp[i2] = (__bf16)v;
  }
}

// ---- GEMM1 (MFMA): Yb[N][128] = bf16( X[N][256] @ W1 ) ------------------
// Weights staged in LDS so the K-loop's vmcnt queue carries ONLY the X
// stream (lgkmcnt carries B-frags) — decoupled wait counters let the
// compiler keep X prefetches in flight. Persistent tile loop (LDS staging
// amortized; 64 KB LDS -> 2 blocks/CU).

__global__ __launch_bounds__(256) void gemm1_mfma(const float* __restrict__ X,
    const __bf16* __restrict__ Wp, __bf16* __restrict__ Yb, int nrows, int ntiles) {
  __shared__ __bf16 bs[32768];  // 64 KB: full W1 in B-frag order
  const int tid = threadIdx.x;
  {
    const float4* s4 = (const float4*)Wp;
    float4* d4 = (float4*)bs;
#pragma unroll
    for (int i = 0; i < 16; ++i) d4[tid + 256 * i] = s4[tid + 256 * i];
  }
  __syncthreads();
  const int lane = tid & 63;
  const int wave = tid >> 6;
  const int lm = lane & 15;
  const int q = lane >> 4;
  const bf16x8* bsv = (const bf16x8*)bs;

  for (int tile = blockIdx.x; tile < ntiles; tile += gridDim.x) {
    const int rb = tile * 128 + wave * 32;
    int r0 = min(rb + lm, nrows - 1);
    int r1 = min(rb + 16 + lm, nrows - 1);
    const float* x0 = X + (size_t)r0 * N_FEATS_IN + q * 8;
    const float* x1 = X + (size_t)r1 * N_FEATS_IN + q * 8;

    f32x4 acc[2][8];
#pragma unroll
    for (int m = 0; m < 2; ++m)
#pragma unroll
      for (int t = 0; t < 8; ++t) acc[m][t] = (f32x4)0.f;

#pragma unroll
    for (int s = 0; s < 8; ++s) {
      float4 u0 = ((const float4*)(x0 + s * 32))[0];
      float4 v0 = ((const float4*)(x0 + s * 32))[1];
      float4 u1 = ((const float4*)(x1 + s * 32))[0];
      float4 v1 = ((const float4*)(x1 + s * 32))[1];
      bf16x8 a0, a1;
      a0[0] = (__bf16)u0.x; a0[1] = (__bf16)u0.y; a0[2] = (__bf16)u0.z; a0[3] = (__bf16)u0.w;
      a0[4] = (__bf16)v0.x; a0[5] = (__bf16)v0.y; a0[6] = (__bf16)v0.z; a0[7] = (__bf16)v0.w;
      a1[0] = (__bf16)u1.x; a1[1] = (__bf16)u1.y; a1[2] = (__bf16)u1.z; a1[3] = (__bf16)u1.w;
      a1[4] = (__bf16)v1.x; a1[5] = (__bf16)v1.y; a1[6] = (__bf16)v1.z; a1[7] = (__bf16)v1.w;
#pragma unroll
      for (int t = 0; t < 8; ++t) {
        bf16x8 b = bsv[(s * 8 + t) * 64 + lane];
        acc[0][t] = __builtin_amdgcn_mfma_f32_16x16x32_bf16(a0, b, acc[0][t], 0, 0, 0);
        acc[1][t] = __builtin_amdgcn_mfma_f32_16x16x32_bf16(a1, b, acc[1][t], 0, 0, 0);
      }
    }
    // D: col = lane&15, row = q*4 + reg
#pragma unroll
    for (int m = 0; m < 2; ++m) {
      int rowbase = rb + m * 16 + q * 4;
#pragma unroll
      for (int t = 0; t < 8; ++t) {
#pragma unroll
        for (int r = 0; r < 4; ++r) {
          int row = rowbase + r;
          if (row < nrows) Yb[(size_t)row * HID + t * 16 + lm] = (__bf16)acc[m][t][r];
        }
      }
    }
  }
}

// ---- aggregation (bf16 in/out, f32 accumulate) --------------------------
// Fout[c] = dinv[c]^2*Fin[c] + sum_e norm[e]*Fin[src[e]]; 1 wave/node, 2 feats/lane

__global__ __launch_bounds__(64) void agg_kernel(const __bf16* __restrict__ Fin,
    const int* __restrict__ ptr, const int2* __restrict__ erec,
    const float* __restrict__ dinv, const float* __restrict__ bias,
    __bf16* __restrict__ Fout, int do_relu) {
  const int c = blockIdx.x;
  const int t = threadIdx.x;
  const float d = dinv[c];
  bf16x2 sv = ((const bf16x2*)(Fin + (size_t)c * HID))[t];
  float ax = d * d * (float)sv[0];
  float ay = d * d * (float)sv[1];
  const int beg = ptr[c], end = ptr[c + 1];
  int e = beg;
  for (; e + 4 <= end; e += 4) {
    int2 p0 = erec[e], p1 = erec[e + 1], p2 = erec[e + 2], p3 = erec[e + 3];
    float n0 = __int_as_float(p0.y), n1 = __int_as_float(p1.y);
    float n2 = __int_as_float(p2.y), n3 = __int_as_float(p3.y);
    bf16x2 v0 = ((const bf16x2*)(Fin + (size_t)p0.x * HID))[t];
    bf16x2 v1 = ((const bf16x2*)(Fin + (size_t)p1.x * HID))[t];
    bf16x2 v2 = ((const bf16x2*)(Fin + (size_t)p2.x * HID))[t];
    bf16x2 v3 = ((const bf16x2*)(Fin + (size_t)p3.x * HID))[t];
    ax = fmaf(n0, (float)v0[0], ax); ay = fmaf(n0, (float)v0[1], ay);
    ax = fmaf(n1, (float)v1[0], ax); ay = fmaf(n1, (float)v1[1], ay);
    ax = fmaf(n2, (float)v2[0], ax); ay = fmaf(n2, (float)v2[1], ay);
    ax = fmaf(n3, (float)v3[0], ax); ay = fmaf(n3, (float)v3[1], ay);
  }
  for (; e < end; ++e) {
    int2 p = erec[e];
    float nn = __int_as_float(p.y);
    bf16x2 v = ((const bf16x2*)(Fin + (size_t)p.x * HID))[t];
    ax = fmaf(nn, (float)v[0], ax);
    ay = fmaf(nn, (float)v[1], ay);
  }
  if (do_relu) {
    ax = fmaxf(ax + bias[2 * t], 0.f);
    ay = fmaxf(ay + bias[2 * t + 1], 0.f);
  }
  bf16x2 o;
  o[0] = (__bf16)ax;
  o[1] = (__bf16)ay;
  ((bf16x2*)(Fout + (size_t)c * HID))[t] = o;
}

// ---- GEMM2 (MFMA): [mu|lv] = Gb[N][128] @ Wc[128][128] + bias -----------
// Same LDS weight staging (32 KB) as gemm1.

__global__ __launch_bounds__(256) void gemm2_mfma(const __bf16* __restrict__ Gb,
    const __bf16* __restrict__ Wp, const float* __restrict__ bmu,
    const float* __restrict__ blv, float* __restrict__ out, int nrows) {
  __shared__ __bf16 bs[16384];  // 32 KB: full Wc in B-frag order
  const int tid = threadIdx.x;
  {
    const float4* s4 = (const float4*)Wp;
    float4* d4 = (float4*)bs;
#pragma unroll
    for (int i = 0; i < 8; ++i) d4[tid + 256 * i] = s4[tid + 256 * i];
  }
  __syncthreads();
  const int lane = tid & 63;
  const int wave = tid >> 6;
  const int rb = blockIdx.x * 128 + wave * 32;
  const int lm = lane & 15;
  const int q = lane >> 4;
  const bf16x8* bsv = (const bf16x8*)bs;

  f32x4 acc[2][8];
#pragma unroll
  for (int m = 0; m < 2; ++m)
#pragma unroll
    for (int t = 0; t < 8; ++t) acc[m][t] = (f32x4)0.f;

  int r0 = min(rb + lm, nrows - 1);
  int r1 = min(rb + 16 + lm, nrows - 1);
  const __bf16* g0 = Gb + (size_t)r0 * HID + q * 8;
  const __bf16* g1 = Gb + (size_t)r1 * HID + q * 8;

#pragma unroll
  for (int s = 0; s < 4; ++s) {
    bf16x8 a0 = *(const bf16x8*)(g0 + s * 32);
    bf16x8 a1 = *(const bf16x8*)(g1 + s * 32);
#pragma unroll
    for (int t = 0; t < 8; ++t) {
      bf16x8 b = bsv[(s * 8 + t) * 64 + lane];
      acc[0][t] = __builtin_amdgcn_mfma_f32_16x16x32_bf16(a0, b, acc[0][t], 0, 0, 0);
      acc[1][t] = __builtin_amdgcn_mfma_f32_16x16x32_bf16(a1, b, acc[1][t], 0, 0, 0);
    }
  }
#pragma unroll
  for (int m = 0; m < 2; ++m) {
    int rowbase = rb + m * 16 + q * 4;
#pragma unroll
    for (int t = 0; t < 8; ++t) {
      int g = t * 16 + lm;
      float bv = (g < OUTF) ? bmu[g] : blv[g - OUTF];
      float* ob = (g < OUTF) ? (out + g) : (out + (size_t)nrows * OUTF + (g - OUTF));
#pragma unroll
      for (int r = 0; r < 4; ++r) {
        int row = rowbase + r;
        if (row < nrows) ob[(size_t)row * OUTF] = acc[m][t][r] + bv;
      }
    }
  }
}

// ---- launch -------------------------------------------------------------

extern "C" void kernel_launch(void* const* d_in, const int* in_sizes, int n_in,
                              void* d_out, int out_size, void* d_ws, size_t ws_size,
                              hipStream_t stream) {
  const float* X   = (const float*)d_in[0];
  const int*   ei  = (const int*)d_in[1];
  const float* W1  = (const float*)d_in[2];
  const float* b1  = (const float*)d_in[3];
  const float* Wmu = (const float*)d_in[4];
  const float* bmu = (const float*)d_in[5];
  const float* Wlv = (const float*)d_in[6];
  const float* blv = (const float*)d_in[7];
  float* out = (float*)d_out;

  const int N = in_sizes[0] / N_FEATS_IN;   // 100000
  const int E = in_sizes[1] / 2;            // 1600000

  char* ws = (char*)d_ws;
  size_t off = 0;
  auto alloc = [&](size_t bytes) -> void* {
    void* p = ws + off;
    off += (bytes + 255) & ~(size_t)255;
    return p;
  };
  __bf16* Yb  = (__bf16*)alloc((size_t)N * HID * 2);  // gemm1 out; reused as G
  __bf16* Hb  = (__bf16*)alloc((size_t)N * HID * 2);  // relu(Â Y + b1)
  float* dinv = (float*)alloc((size_t)N * 4);
  int*   deg  = (int*)alloc((size_t)N * 4);
  int*   ptr  = (int*)alloc((size_t)(N + 1) * 4);
  int*   cnt8 = (int*)alloc((size_t)NXCD * N * 4);  // per-XCD histogram -> offsets
  int*   erank = (int*)alloc((size_t)E * 4);
  int2*  erec = (int2*)alloc((size_t)E * 8);
  __bf16* W1p = (__bf16*)alloc(32768 * 2);
  __bf16* Wcp = (__bf16*)alloc(16384 * 2);
  int*   bsum = (int*)alloc(256 * 4);
  (void)ws_size; (void)n_in; (void)out_size;

  hipMemsetAsync(cnt8, 0, (size_t)NXCD * N * 4, stream);

  int ge = (E + 255) / 256;
  int gn = (N + 255) / 256;
  int nb = (N + 256 * SITEMS - 1) / (256 * SITEMS);  // 49 blocks for N=100000
  count_deg_kernel<<<ge, 256, 0, stream>>>(ei, E, N, cnt8, erank);
  combine_kernel<<<gn, 256, 0, stream>>>(cnt8, deg, dinv, N);
  scan_part_kernel<<<nb, 256, 0, stream>>>(deg, N, bsum);
  scan_bsum_kernel<<<1, 256, 0, stream>>>(bsum, nb);
  scan_final_kernel<<<nb, 256, 0, stream>>>(deg, N, bsum, ptr);
  fill_kernel<<<ge, 256, 0, stream>>>(ei, E, N, ptr, cnt8, erank, dinv, erec);
  pack_all_kernel<<<192, 256, 0, stream>>>(W1, Wmu, Wlv, W1p, Wcp);

  int ntiles = (N + 127) / 128;
  int g1 = ntiles < 512 ? ntiles : 512;  // 2 blocks/CU (64 KB LDS) x 256 CUs
  gemm1_mfma<<<g1, 256, 0, stream>>>(X, W1p, Yb, N, ntiles);
  agg_kernel<<<N, 64, 0, stream>>>(Yb, ptr, erec, dinv, b1, Hb, 1);  // H = relu(ÂY+b1)
  agg_kernel<<<N, 64, 0, stream>>>(Hb, ptr, erec, dinv, b1, Yb, 0);  // G = ÂH
  gemm2_mfma<<<ntiles, 256, 0, stream>>>(Yb, Wcp, bmu, blv, out, N);
}

// Round 7
// 460.201 us; speedup vs baseline: 1.0475x; 1.0199x over previous
//
#include <hip/hip_runtime.h>
#include <hip/hip_bf16.h>
#include <cstdint>

#define N_FEATS_IN 256
#define HID 128
#define OUTF 64
#define SITEMS 8  // elements per thread in hierarchical scan; 256*8=2048/block
#define NXCD 8

typedef __bf16 bf16x8 __attribute__((ext_vector_type(8)));
typedef __bf16 bf16x2 __attribute__((ext_vector_type(2)));
typedef float f32x4 __attribute__((ext_vector_type(4)));

__device__ __forceinline__ int xcc_id() {
  int x;
  asm volatile("s_getreg_b32 %0, hwreg(HW_REG_XCC_ID, 0, 32)" : "=s"(x));
  return x & (NXCD - 1);
}

__device__ __forceinline__ bf16x8 cvt8(float4 u, float4 v) {
  bf16x8 a;
  a[0] = (__bf16)u.x; a[1] = (__bf16)u.y; a[2] = (__bf16)u.z; a[3] = (__bf16)u.w;
  a[4] = (__bf16)v.x; a[5] = (__bf16)v.y; a[6] = (__bf16)v.z; a[7] = (__bf16)v.w;
  return a;
}

// ---- CSR build ----------------------------------------------------------
// XCD-private histograms: atomics stay in the local L2 (workgroup scope);
// slice x is only ever touched by workgroups physically on XCD x.

__global__ __launch_bounds__(256) void count_deg_kernel(const int* __restrict__ ei, int E,
    int N, int* __restrict__ cnt8, int* __restrict__ erank) {
  int e = blockIdx.x * 256 + threadIdx.x;
  int x = xcc_id();
  if (e < E) {
    int c = ei[E + e];  // target
    int lr = __hip_atomic_fetch_add(&cnt8[(size_t)x * N + c], 1,
                                    __ATOMIC_RELAXED, __HIP_MEMORY_SCOPE_WORKGROUP);
    erank[e] = lr | (x << 28);
  }
}

// deg[c] = sum over slices; cnt8[x][c] becomes the per-XCD exclusive offset.
__global__ __launch_bounds__(256) void combine_kernel(int* __restrict__ cnt8,
    int* __restrict__ deg, float* __restrict__ dinv, int n) {
  int c = blockIdx.x * 256 + threadIdx.x;
  if (c < n) {
    int s = 0;
#pragma unroll
    for (int x = 0; x < NXCD; ++x) {
      int v = cnt8[(size_t)x * n + c];
      cnt8[(size_t)x * n + c] = s;
      s += v;
    }
    deg[c] = s;
    dinv[c] = rsqrtf((float)(s + 1));  // +1 self-loop
  }
}

// ---- hierarchical exclusive scan: ptr[0..n], ptr[n] = total -------------

__global__ __launch_bounds__(256) void scan_part_kernel(const int* __restrict__ cnt, int n,
                                                        int* __restrict__ bsum) {
  __shared__ int ts[256];
  const int t = threadIdx.x;
  int base = (blockIdx.x * 256 + t) * SITEMS;
  int s = 0;
#pragma unroll
  for (int i = 0; i < SITEMS; ++i) {
    int idx = base + i;
    if (idx < n) s += cnt[idx];
  }
  ts[t] = s;
  __syncthreads();
  for (int off = 128; off > 0; off >>= 1) {
    if (t < off) ts[t] += ts[t + off];
    __syncthreads();
  }
  if (t == 0) bsum[blockIdx.x] = ts[0];
}

__global__ __launch_bounds__(256) void scan_bsum_kernel(int* __restrict__ bsum, int nb) {
  __shared__ int ts[256];
  const int t = threadIdx.x;
  int v = (t < nb) ? bsum[t] : 0;
  ts[t] = v;
  __syncthreads();
  for (int off = 1; off < 256; off <<= 1) {
    int u = (t >= off) ? ts[t - off] : 0;
    __syncthreads();
    ts[t] += u;
    __syncthreads();
  }
  if (t < nb) bsum[t] = ts[t] - v;  // exclusive
}

__global__ __launch_bounds__(256) void scan_final_kernel(const int* __restrict__ cnt, int n,
    const int* __restrict__ bsum, int* __restrict__ ptr) {
  __shared__ int ts[256];
  const int t = threadIdx.x;
  int base = (blockIdx.x * 256 + t) * SITEMS;
  int loc[SITEMS];
  int s = 0;
#pragma unroll
  for (int i = 0; i < SITEMS; ++i) {
    int idx = base + i;
    loc[i] = (idx < n) ? cnt[idx] : 0;
    s += loc[i];
  }
  ts[t] = s;
  __syncthreads();
  for (int off = 1; off < 256; off <<= 1) {
    int u = (t >= off) ? ts[t - off] : 0;
    __syncthreads();
    ts[t] += u;
    __syncthreads();
  }
  int run = bsum[blockIdx.x] + ts[t] - s;  // exclusive prefix for this thread
#pragma unroll
  for (int i = 0; i < SITEMS; ++i) {
    int idx = base + i;
    if (idx < n) ptr[idx] = run;
    run += loc[i];
  }
  if (base < n && base + SITEMS >= n) ptr[n] = run;  // thread covering n-1
}

// no atomic: pos = ptr[c] + offs[xcd][c] + local_rank; one 8B store per edge

__global__ __launch_bounds__(256) void fill_kernel(const int* __restrict__ ei, int E, int N,
    const int* __restrict__ ptr, const int* __restrict__ offs, const int* __restrict__ erank,
    const float* __restrict__ dinv, int2* __restrict__ erec) {
  int e = blockIdx.x * 256 + threadIdx.x;
  if (e < E) {
    int r = ei[e];       // source
    int c = ei[E + e];   // target
    int er = erank[e];
    int x = er >> 28;
    int lr = er & 0x0FFFFFFF;
    int pos = ptr[c] + offs[(size_t)x * N + c] + lr;
    int2 rec;
    rec.x = r;
    rec.y = __float_as_int(dinv[r] * dinv[c]);
    erec[pos] = rec;
  }
}

// ---- weight repack into MFMA B-fragment order (one kernel) --------------
// B-frag for mfma_f32_16x16x32_bf16: lane l holds B[k = (l>>4)*8 + j][n = l&15]

__global__ __launch_bounds__(256) void pack_all_kernel(const float* __restrict__ W1,
    const float* __restrict__ Wmu, const float* __restrict__ Wlv,
    __bf16* __restrict__ W1p, __bf16* __restrict__ Wcp) {
  int idx = blockIdx.x * 256 + threadIdx.x;  // 32768 + 16384 = 49152
  if (idx < 32768) {
    int j = idx & 7, l = (idx >> 3) & 63, t = (idx >> 9) & 7, s = idx >> 12;
    int k = s * 32 + (l >> 4) * 8 + j;
    int n = t * 16 + (l & 15);
    W1p[idx] = (__bf16)W1[k * HID + n];
  } else if (idx < 49152) {
    int i2 = idx - 32768;
    int j = i2 & 7, l = (i2 >> 3) & 63, t = (i2 >> 9) & 7, s = i2 >> 12;
    int k = s * 32 + (l >> 4) * 8 + j;
    int g = t * 16 + (l & 15);
    float v = (g < OUTF) ? Wmu[k * OUTF + g] : Wlv[k * OUTF + (g - OUTF)];
    Wcp[i2] = (__bf16)v;
  }
}

// ---- GEMM1 (MFMA): Yb[N][128] = bf16( X[N][256] @ W1 ) ------------------
// MLP-first structure: each wave owns 16 rows; ALL 16 X float4 loads for the
// full K=256 are issued as one batch before any compute, so the compiler
// drains vmcnt incrementally and keeps ~14 loads/lane in flight. B-frags
// come from LDS (lgkmcnt — independent counter). Persistent grid-stride.

__global__ __launch_bounds__(256) void gemm1_mfma(const float* __restrict__ X,
    const __bf16* __restrict__ Wp, __bf16* __restrict__ Yb, int nrows, int ntiles) {
  __shared__ __bf16 bs[32768];  // 64 KB: full W1 in B-frag order
  const int tid = threadIdx.x;
  {
    const float4* s4 = (const float4*)Wp;
    float4* d4 = (float4*)bs;
#pragma unroll
    for (int i = 0; i < 16; ++i) d4[tid + 256 * i] = s4[tid + 256 * i];
  }
  __syncthreads();
  const int lane = tid & 63;
  const int wave = tid >> 6;
  const int lm = lane & 15;
  const int q = lane >> 4;
  const bf16x8* bsv = (const bf16x8*)bs;

  for (int tile = blockIdx.x; tile < ntiles; tile += gridDim.x) {
    const int row0 = tile * 64 + wave * 16;
    const int r = min(row0 + lm, nrows - 1);
    const float4* xp = (const float4*)(X + (size_t)r * N_FEATS_IN) + q * 2;

    // hoisted batch: entire K for this lane's row (16 loads in flight)
    float4 xa[16];
#pragma unroll
    for (int s = 0; s < 8; ++s) {
      xa[2 * s]     = xp[s * 8];
      xa[2 * s + 1] = xp[s * 8 + 1];
    }

    f32x4 acc[8];
#pragma unroll
    for (int t = 0; t < 8; ++t) acc[t] = (f32x4)0.f;

#pragma unroll
    for (int s = 0; s < 8; ++s) {
      bf16x8 a = cvt8(xa[2 * s], xa[2 * s + 1]);
#pragma unroll
      for (int t = 0; t < 8; ++t)
        acc[t] = __builtin_amdgcn_mfma_f32_16x16x32_bf16(a, bsv[(s * 8 + t) * 64 + lane],
                                                         acc[t], 0, 0, 0);
    }
    // D: col = t*16 + lm, row = row0 + q*4 + r2
#pragma unroll
    for (int t = 0; t < 8; ++t) {
#pragma unroll
      for (int r2 = 0; r2 < 4; ++r2) {
        int row = row0 + q * 4 + r2;
        if (row < nrows) Yb[(size_t)row * HID + t * 16 + lm] = (__bf16)acc[t][r2];
      }
    }
  }
}

// ---- aggregation (bf16 in/out, f32 accumulate) --------------------------
// Fout[c] = dinv[c]^2*Fin[c] + sum_e norm[e]*Fin[src[e]]; 1 wave/node, 2 feats/lane

__global__ __launch_bounds__(64) void agg_kernel(const __bf16* __restrict__ Fin,
    const int* __restrict__ ptr, const int2* __restrict__ erec,
    const float* __restrict__ dinv, const float* __restrict__ bias,
    __bf16* __restrict__ Fout, int do_relu) {
  const int c = blockIdx.x;
  const int t = threadIdx.x;
  const float d = dinv[c];
  bf16x2 sv = ((const bf16x2*)(Fin + (size_t)c * HID))[t];
  float ax = d * d * (float)sv[0];
  float ay = d * d * (float)sv[1];
  const int beg = ptr[c], end = ptr[c + 1];
  int e = beg;
  for (; e + 4 <= end; e += 4) {
    int2 p0 = erec[e], p1 = erec[e + 1], p2 = erec[e + 2], p3 = erec[e + 3];
    float n0 = __int_as_float(p0.y), n1 = __int_as_float(p1.y);
    float n2 = __int_as_float(p2.y), n3 = __int_as_float(p3.y);
    bf16x2 v0 = ((const bf16x2*)(Fin + (size_t)p0.x * HID))[t];
    bf16x2 v1 = ((const bf16x2*)(Fin + (size_t)p1.x * HID))[t];
    bf16x2 v2 = ((const bf16x2*)(Fin + (size_t)p2.x * HID))[t];
    bf16x2 v3 = ((const bf16x2*)(Fin + (size_t)p3.x * HID))[t];
    ax = fmaf(n0, (float)v0[0], ax); ay = fmaf(n0, (float)v0[1], ay);
    ax = fmaf(n1, (float)v1[0], ax); ay = fmaf(n1, (float)v1[1], ay);
    ax = fmaf(n2, (float)v2[0], ax); ay = fmaf(n2, (float)v2[1], ay);
    ax = fmaf(n3, (float)v3[0], ax); ay = fmaf(n3, (float)v3[1], ay);
  }
  for (; e < end; ++e) {
    int2 p = erec[e];
    float nn = __int_as_float(p.y);
    bf16x2 v = ((const bf16x2*)(Fin + (size_t)p.x * HID))[t];
    ax = fmaf(nn, (float)v[0], ax);
    ay = fmaf(nn, (float)v[1], ay);
  }
  if (do_relu) {
    ax = fmaxf(ax + bias[2 * t], 0.f);
    ay = fmaxf(ay + bias[2 * t + 1], 0.f);
  }
  bf16x2 o;
  o[0] = (__bf16)ax;
  o[1] = (__bf16)ay;
  ((bf16x2*)(Fout + (size_t)c * HID))[t] = o;
}

// ---- GEMM2 (MFMA): [mu|lv] = Gb[N][128] @ Wc[128][128] + bias -----------
// Same MLP-first structure: 16 rows/wave, all 4 A loads hoisted, B in LDS.

__global__ __launch_bounds__(256) void gemm2_mfma(const __bf16* __restrict__ Gb,
    const __bf16* __restrict__ Wp, const float* __restrict__ bmu,
    const float* __restrict__ blv, float* __restrict__ out, int nrows, int ntiles) {
  __shared__ __bf16 bs[16384];  // 32 KB: full Wc in B-frag order
  const int tid = threadIdx.x;
  {
    const float4* s4 = (const float4*)Wp;
    float4* d4 = (float4*)bs;
#pragma unroll
    for (int i = 0; i < 8; ++i) d4[tid + 256 * i] = s4[tid + 256 * i];
  }
  __syncthreads();
  const int lane = tid & 63;
  const int wave = tid >> 6;
  const int lm = lane & 15;
  const int q = lane >> 4;
  const bf16x8* bsv = (const bf16x8*)bs;

  // per-lane bias + output base (fixed for all tiles)
  const int g = (lane & 15) * 1;  // col within [mu|lv] = t*16 + lm; t varies below
  float bv[8];
  size_t obase[8];
#pragma unroll
  for (int t = 0; t < 8; ++t) {
    int col = t * 16 + (lane & 15);
    bv[t] = (col < OUTF) ? bmu[col] : blv[col - OUTF];
    obase[t] = (col < OUTF) ? (size_t)col : ((size_t)nrows * OUTF + (col - OUTF));
  }
  (void)g;

  for (int tile = blockIdx.x; tile < ntiles; tile += gridDim.x) {
    const int row0 = tile * 64 + wave * 16;
    const int r = min(row0 + lm, nrows - 1);
    const bf16x8* gp = (const bf16x8*)(Gb + (size_t)r * HID);

    bf16x8 xa[4];
#pragma unroll
    for (int s = 0; s < 4; ++s) xa[s] = gp[s * 4 + q];

    f32x4 acc[8];
#pragma unroll
    for (int t = 0; t < 8; ++t) acc[t] = (f32x4)0.f;

#pragma unroll
    for (int s = 0; s < 4; ++s) {
#pragma unroll
      for (int t = 0; t < 8; ++t)
        acc[t] = __builtin_amdgcn_mfma_f32_16x16x32_bf16(xa[s], bsv[(s * 8 + t) * 64 + lane],
                                                         acc[t], 0, 0, 0);
    }
#pragma unroll
    for (int t = 0; t < 8; ++t) {
#pragma unroll
      for (int r2 = 0; r2 < 4; ++r2) {
        int row = row0 + q * 4 + r2;
        if (row < nrows) out[obase[t] + (size_t)row * OUTF] = acc[t][r2] + bv[t];
      }
    }
  }
}

// ---- launch -------------------------------------------------------------

extern "C" void kernel_launch(void* const* d_in, const int* in_sizes, int n_in,
                              void* d_out, int out_size, void* d_ws, size_t ws_size,
                              hipStream_t stream) {
  const float* X   = (const float*)d_in[0];
  const int*   ei  = (const int*)d_in[1];
  const float* W1  = (const float*)d_in[2];
  const float* b1  = (const float*)d_in[3];
  const float* Wmu = (const float*)d_in[4];
  const float* bmu = (const float*)d_in[5];
  const float* Wlv = (const float*)d_in[6];
  const float* blv = (const float*)d_in[7];
  float* out = (float*)d_out;

  const int N = in_sizes[0] / N_FEATS_IN;   // 100000
  const int E = in_sizes[1] / 2;            // 1600000

  char* ws = (char*)d_ws;
  size_t off = 0;
  auto alloc = [&](size_t bytes) -> void* {
    void* p = ws + off;
    off += (bytes + 255) & ~(size_t)255;
    return p;
  };
  __bf16* Yb  = (__bf16*)alloc((size_t)N * HID * 2);  // gemm1 out; reused as G
  __bf16* Hb  = (__bf16*)alloc((size_t)N * HID * 2);  // relu(Â Y + b1)
  float* dinv = (float*)alloc((size_t)N * 4);
  int*   deg  = (int*)alloc((size_t)N * 4);
  int*   ptr  = (int*)alloc((size_t)(N + 1) * 4);
  int*   cnt8 = (int*)alloc((size_t)NXCD * N * 4);  // per-XCD histogram -> offsets
  int*   erank = (int*)alloc((size_t)E * 4);
  int2*  erec = (int2*)alloc((size_t)E * 8);
  __bf16* W1p = (__bf16*)alloc(32768 * 2);
  __bf16* Wcp = (__bf16*)alloc(16384 * 2);
  int*   bsum = (int*)alloc(256 * 4);
  (void)ws_size; (void)n_in; (void)out_size;

  hipMemsetAsync(cnt8, 0, (size_t)NXCD * N * 4, stream);

  int ge = (E + 255) / 256;
  int gn = (N + 255) / 256;
  int nb = (N + 256 * SITEMS - 1) / (256 * SITEMS);  // 49 blocks for N=100000
  count_deg_kernel<<<ge, 256, 0, stream>>>(ei, E, N, cnt8, erank);
  combine_kernel<<<gn, 256, 0, stream>>>(cnt8, deg, dinv, N);
  scan_part_kernel<<<nb, 256, 0, stream>>>(deg, N, bsum);
  scan_bsum_kernel<<<1, 256, 0, stream>>>(bsum, nb);
  scan_final_kernel<<<nb, 256, 0, stream>>>(deg, N, bsum, ptr);
  fill_kernel<<<ge, 256, 0, stream>>>(ei, E, N, ptr, cnt8, erank, dinv, erec);
  pack_all_kernel<<<192, 256, 0, stream>>>(W1, Wmu, Wlv, W1p, Wcp);

  int ntiles = (N + 63) / 64;               // 16 rows/wave x 4 waves
  int g1 = ntiles < 512 ? ntiles : 512;     // 2 blocks/CU (64 KB LDS)
  int g2 = ntiles < 768 ? ntiles : 768;
  gemm1_mfma<<<g1, 256, 0, stream>>>(X, W1p, Yb, N, ntiles);
  agg_kernel<<<N, 64, 0, stream>>>(Yb, ptr, erec, dinv, b1, Hb, 1);  // H = relu(ÂY+b1)
  agg_kernel<<<N, 64, 0, stream>>>(Hb, ptr, erec, dinv, b1, Yb, 0);  // G = ÂH
  gemm2_mfma<<<g2, 256, 0, stream>>>(Yb, Wcp, bmu, blv, out, N, ntiles);
}

// Round 8
// 455.943 us; speedup vs baseline: 1.0573x; 1.0093x over previous
//
#include <hip/hip_runtime.h>
#include <hip/hip_bf16.h>
#include <cstdint>

#define N_FEATS_IN 256
#define HID 128
#define OUTF 64
#define SITEMS 8
#define NXCD 8
#define XS_STRIDE 264  // bf16 per LDS row: 256 + 8 pad -> 528 B, 16B-aligned, bank-safe

typedef __bf16 bf16x8 __attribute__((ext_vector_type(8)));
typedef __bf16 bf16x4 __attribute__((ext_vector_type(4)));
typedef __bf16 bf16x2 __attribute__((ext_vector_type(2)));
typedef float f32x4 __attribute__((ext_vector_type(4)));

__device__ __forceinline__ int xcc_id() {
  int x;
  asm volatile("s_getreg_b32 %0, hwreg(HW_REG_XCC_ID, 0, 32)" : "=s"(x));
  return x & (NXCD - 1);
}

// ---- CSR build ----------------------------------------------------------

__global__ __launch_bounds__(256) void count_deg_kernel(const int* __restrict__ ei, int E,
    int N, int* __restrict__ cnt8, int* __restrict__ erank) {
  int e = blockIdx.x * 256 + threadIdx.x;
  int x = xcc_id();
  if (e < E) {
    int c = ei[E + e];  // target
    int lr = __hip_atomic_fetch_add(&cnt8[(size_t)x * N + c], 1,
                                    __ATOMIC_RELAXED, __HIP_MEMORY_SCOPE_WORKGROUP);
    erank[e] = lr | (x << 28);
  }
}

__global__ __launch_bounds__(256) void combine_kernel(int* __restrict__ cnt8,
    int* __restrict__ deg, float* __restrict__ dinv, int n) {
  int c = blockIdx.x * 256 + threadIdx.x;
  if (c < n) {
    int s = 0;
#pragma unroll
    for (int x = 0; x < NXCD; ++x) {
      int v = cnt8[(size_t)x * n + c];
      cnt8[(size_t)x * n + c] = s;
      s += v;
    }
    deg[c] = s;
    dinv[c] = rsqrtf((float)(s + 1));  // +1 self-loop
  }
}

// ---- hierarchical exclusive scan: ptr[0..n], ptr[n] = total -------------

__global__ __launch_bounds__(256) void scan_part_kernel(const int* __restrict__ cnt, int n,
                                                        int* __restrict__ bsum) {
  __shared__ int ts[256];
  const int t = threadIdx.x;
  int base = (blockIdx.x * 256 + t) * SITEMS;
  int s = 0;
#pragma unroll
  for (int i = 0; i < SITEMS; ++i) {
    int idx = base + i;
    if (idx < n) s += cnt[idx];
  }
  ts[t] = s;
  __syncthreads();
  for (int off = 128; off > 0; off >>= 1) {
    if (t < off) ts[t] += ts[t + off];
    __syncthreads();
  }
  if (t == 0) bsum[blockIdx.x] = ts[0];
}

__global__ __launch_bounds__(256) void scan_bsum_kernel(int* __restrict__ bsum, int nb) {
  __shared__ int ts[256];
  const int t = threadIdx.x;
  int v = (t < nb) ? bsum[t] : 0;
  ts[t] = v;
  __syncthreads();
  for (int off = 1; off < 256; off <<= 1) {
    int u = (t >= off) ? ts[t - off] : 0;
    __syncthreads();
    ts[t] += u;
    __syncthreads();
  }
  if (t < nb) bsum[t] = ts[t] - v;  // exclusive
}

__global__ __launch_bounds__(256) void scan_final_kernel(const int* __restrict__ cnt, int n,
    const int* __restrict__ bsum, int* __restrict__ ptr) {
  __shared__ int ts[256];
  const int t = threadIdx.x;
  int base = (blockIdx.x * 256 + t) * SITEMS;
  int loc[SITEMS];
  int s = 0;
#pragma unroll
  for (int i = 0; i < SITEMS; ++i) {
    int idx = base + i;
    loc[i] = (idx < n) ? cnt[idx] : 0;
    s += loc[i];
  }
  ts[t] = s;
  __syncthreads();
  for (int off = 1; off < 256; off <<= 1) {
    int u = (t >= off) ? ts[t - off] : 0;
    __syncthreads();
    ts[t] += u;
    __syncthreads();
  }
  int run = bsum[blockIdx.x] + ts[t] - s;
#pragma unroll
  for (int i = 0; i < SITEMS; ++i) {
    int idx = base + i;
    if (idx < n) ptr[idx] = run;
    run += loc[i];
  }
  if (base < n && base + SITEMS >= n) ptr[n] = run;
}

__global__ __launch_bounds__(256) void fill_kernel(const int* __restrict__ ei, int E, int N,
    const int* __restrict__ ptr, const int* __restrict__ offs, const int* __restrict__ erank,
    const float* __restrict__ dinv, int2* __restrict__ erec) {
  int e = blockIdx.x * 256 + threadIdx.x;
  if (e < E) {
    int r = ei[e];
    int c = ei[E + e];
    int er = erank[e];
    int x = er >> 28;
    int lr = er & 0x0FFFFFFF;
    int pos = ptr[c] + offs[(size_t)x * N + c] + lr;
    int2 rec;
    rec.x = r;
    rec.y = __float_as_int(dinv[r] * dinv[c]);
    erec[pos] = rec;
  }
}

// ---- weight repack into MFMA B-fragment order ---------------------------

__global__ __launch_bounds__(256) void pack_all_kernel(const float* __restrict__ W1,
    const float* __restrict__ Wmu, const float* __restrict__ Wlv,
    __bf16* __restrict__ W1p, __bf16* __restrict__ Wcp) {
  int idx = blockIdx.x * 256 + threadIdx.x;  // 32768 + 16384 = 49152
  if (idx < 32768) {
    int j = idx & 7, l = (idx >> 3) & 63, t = (idx >> 9) & 7, s = idx >> 12;
    int k = s * 32 + (l >> 4) * 8 + j;
    int n = t * 16 + (l & 15);
    W1p[idx] = (__bf16)W1[k * HID + n];
  } else if (idx < 49152) {
    int i2 = idx - 32768;
    int j = i2 & 7, l = (i2 >> 3) & 63, t = (i2 >> 9) & 7, s = i2 >> 12;
    int k = s * 32 + (l >> 4) * 8 + j;
    int g = t * 16 + (l & 15);
    float v = (g < OUTF) ? Wmu[k * OUTF + g] : Wlv[k * OUTF + (g - OUTF)];
    Wcp[i2] = (__bf16)v;
  }
}

// ---- GEMM1 (MFMA): Yb[N][128] = bf16( X[N][256] @ W1 ) ------------------
// SEQUENTIAL X access: block stages its 128-row tile (contiguous 128 KB of
// X) into LDS with coalesced 16B/lane loads (bf16-converted, padded rows),
// then waves read A-frags via ds_read_b128. Kills the 16-row-strided
// per-wave streams that were thrashing DRAM pages. B-frags from global
// (64 KB, L1-hot).

__global__ __launch_bounds__(256) void gemm1_mfma(const float* __restrict__ X,
    const __bf16* __restrict__ Wp, __bf16* __restrict__ Yb, int nrows) {
  __shared__ __bf16 xs[128 * XS_STRIDE];  // 66 KB
  const int tid = threadIdx.x;
  const int rowbase = blockIdx.x * 128;

  // stage 128 rows x 256 feats (f32 -> bf16): 8192 float4, 32 per thread
#pragma unroll
  for (int i = 0; i < 32; ++i) {
    int idx = i * 256 + tid;
    int row = idx >> 6;        // 64 float4 per row
    int cc = idx & 63;
    int gr = min(rowbase + row, nrows - 1);
    float4 v = ((const float4*)(X + (size_t)gr * N_FEATS_IN))[cc];
    bf16x4 b;
    b[0] = (__bf16)v.x; b[1] = (__bf16)v.y; b[2] = (__bf16)v.z; b[3] = (__bf16)v.w;
    *(bf16x4*)(xs + row * XS_STRIDE + cc * 4) = b;
  }
  __syncthreads();

  const int lane = tid & 63;
  const int wave = tid >> 6;
  const int lm = lane & 15;
  const int q = lane >> 4;
  const bf16x8* wp = (const bf16x8*)Wp;

  f32x4 acc[2][8];
#pragma unroll
  for (int m = 0; m < 2; ++m)
#pragma unroll
    for (int t = 0; t < 8; ++t) acc[m][t] = (f32x4)0.f;

  // wave owns rows wave*32 .. wave*32+31 (two 16-row m-sets)
#pragma unroll
  for (int s = 0; s < 8; ++s) {
    // A-frag: lane (lm,q) holds A[row][s*32 + q*8 + j]
    bf16x8 a0 = *(const bf16x8*)(xs + (wave * 32 + lm) * XS_STRIDE + s * 32 + q * 8);
    bf16x8 a1 = *(const bf16x8*)(xs + (wave * 32 + 16 + lm) * XS_STRIDE + s * 32 + q * 8);
#pragma unroll
    for (int t = 0; t < 8; ++t) {
      bf16x8 b = wp[(s * 8 + t) * 64 + lane];
      acc[0][t] = __builtin_amdgcn_mfma_f32_16x16x32_bf16(a0, b, acc[0][t], 0, 0, 0);
      acc[1][t] = __builtin_amdgcn_mfma_f32_16x16x32_bf16(a1, b, acc[1][t], 0, 0, 0);
    }
  }
  // D: col = t*16 + lm, row = base + m*16 + q*4 + r2
#pragma unroll
  for (int m = 0; m < 2; ++m) {
    int rb = rowbase + wave * 32 + m * 16 + q * 4;
#pragma unroll
    for (int t = 0; t < 8; ++t) {
#pragma unroll
      for (int r2 = 0; r2 < 4; ++r2) {
        int row = rb + r2;
        if (row < nrows) Yb[(size_t)row * HID + t * 16 + lm] = (__bf16)acc[m][t][r2];
      }
    }
  }
}

// ---- aggregation (bf16 in/out, f32 accumulate) --------------------------
// Fout[c] = dinv[c]^2*Fin[c] + sum_e norm[e]*Fin[src[e]]; 1 wave/node,
// 2 feats/lane; 8-deep unroll for gather MLP.

__global__ __launch_bounds__(64) void agg_kernel(const __bf16* __restrict__ Fin,
    const int* __restrict__ ptr, const int2* __restrict__ erec,
    const float* __restrict__ dinv, const float* __restrict__ bias,
    __bf16* __restrict__ Fout, int do_relu) {
  const int c = blockIdx.x;
  const int t = threadIdx.x;
  const float d = dinv[c];
  bf16x2 sv = ((const bf16x2*)(Fin + (size_t)c * HID))[t];
  float ax = d * d * (float)sv[0];
  float ay = d * d * (float)sv[1];
  const int beg = ptr[c], end = ptr[c + 1];
  int e = beg;
  for (; e + 8 <= end; e += 8) {
    int2 p[8];
#pragma unroll
    for (int i = 0; i < 8; ++i) p[i] = erec[e + i];
    bf16x2 v[8];
#pragma unroll
    for (int i = 0; i < 8; ++i) v[i] = ((const bf16x2*)(Fin + (size_t)p[i].x * HID))[t];
#pragma unroll
    for (int i = 0; i < 8; ++i) {
      float nn = __int_as_float(p[i].y);
      ax = fmaf(nn, (float)v[i][0], ax);
      ay = fmaf(nn, (float)v[i][1], ay);
    }
  }
  for (; e + 4 <= end; e += 4) {
    int2 p0 = erec[e], p1 = erec[e + 1], p2 = erec[e + 2], p3 = erec[e + 3];
    bf16x2 v0 = ((const bf16x2*)(Fin + (size_t)p0.x * HID))[t];
    bf16x2 v1 = ((const bf16x2*)(Fin + (size_t)p1.x * HID))[t];
    bf16x2 v2 = ((const bf16x2*)(Fin + (size_t)p2.x * HID))[t];
    bf16x2 v3 = ((const bf16x2*)(Fin + (size_t)p3.x * HID))[t];
    float n0 = __int_as_float(p0.y), n1 = __int_as_float(p1.y);
    float n2 = __int_as_float(p2.y), n3 = __int_as_float(p3.y);
    ax = fmaf(n0, (float)v0[0], ax); ay = fmaf(n0, (float)v0[1], ay);
    ax = fmaf(n1, (float)v1[0], ax); ay = fmaf(n1, (float)v1[1], ay);
    ax = fmaf(n2, (float)v2[0], ax); ay = fmaf(n2, (float)v2[1], ay);
    ax = fmaf(n3, (float)v3[0], ax); ay = fmaf(n3, (float)v3[1], ay);
  }
  for (; e < end; ++e) {
    int2 p = erec[e];
    float nn = __int_as_float(p.y);
    bf16x2 v = ((const bf16x2*)(Fin + (size_t)p.x * HID))[t];
    ax = fmaf(nn, (float)v[0], ax);
    ay = fmaf(nn, (float)v[1], ay);
  }
  if (do_relu) {
    ax = fmaxf(ax + bias[2 * t], 0.f);
    ay = fmaxf(ay + bias[2 * t + 1], 0.f);
  }
  bf16x2 o;
  o[0] = (__bf16)ax;
  o[1] = (__bf16)ay;
  ((bf16x2*)(Fout + (size_t)c * HID))[t] = o;
}

// ---- GEMM2 (MFMA): [mu|lv] = Gb[N][128] @ Wc[128][128] + bias -----------

__global__ __launch_bounds__(256) void gemm2_mfma(const __bf16* __restrict__ Gb,
    const __bf16* __restrict__ Wp, const float* __restrict__ bmu,
    const float* __restrict__ blv, float* __restrict__ out, int nrows, int ntiles) {
  __shared__ __bf16 bs[16384];  // 32 KB: full Wc in B-frag order
  const int tid = threadIdx.x;
  {
    const float4* s4 = (const float4*)Wp;
    float4* d4 = (float4*)bs;
#pragma unroll
    for (int i = 0; i < 8; ++i) d4[tid + 256 * i] = s4[tid + 256 * i];
  }
  __syncthreads();
  const int lane = tid & 63;
  const int wave = tid >> 6;
  const int lm = lane & 15;
  const int q = lane >> 4;
  const bf16x8* bsv = (const bf16x8*)bs;

  float bv[8];
  size_t obase[8];
#pragma unroll
  for (int t = 0; t < 8; ++t) {
    int col = t * 16 + lm;
    bv[t] = (col < OUTF) ? bmu[col] : blv[col - OUTF];
    obase[t] = (col < OUTF) ? (size_t)col : ((size_t)nrows * OUTF + (col - OUTF));
  }

  for (int tile = blockIdx.x; tile < ntiles; tile += gridDim.x) {
    const int row0 = tile * 64 + wave * 16;
    const int r = min(row0 + lm, nrows - 1);
    const bf16x8* gp = (const bf16x8*)(Gb + (size_t)r * HID);

    bf16x8 xa[4];
#pragma unroll
    for (int s = 0; s < 4; ++s) xa[s] = gp[s * 4 + q];

    f32x4 acc[8];
#pragma unroll
    for (int t = 0; t < 8; ++t) acc[t] = (f32x4)0.f;

#pragma unroll
    for (int s = 0; s < 4; ++s) {
#pragma unroll
      for (int t = 0; t < 8; ++t)
        acc[t] = __builtin_amdgcn_mfma_f32_16x16x32_bf16(xa[s], bsv[(s * 8 + t) * 64 + lane],
                                                         acc[t], 0, 0, 0);
    }
#pragma unroll
    for (int t = 0; t < 8; ++t) {
#pragma unroll
      for (int r2 = 0; r2 < 4; ++r2) {
        int row = row0 + q * 4 + r2;
        if (row < nrows) out[obase[t] + (size_t)row * OUTF] = acc[t][r2] + bv[t];
      }
    }
  }
}

// ---- launch -------------------------------------------------------------

extern "C" void kernel_launch(void* const* d_in, const int* in_sizes, int n_in,
                              void* d_out, int out_size, void* d_ws, size_t ws_size,
                              hipStream_t stream) {
  const float* X   = (const float*)d_in[0];
  const int*   ei  = (const int*)d_in[1];
  const float* W1  = (const float*)d_in[2];
  const float* b1  = (const float*)d_in[3];
  const float* Wmu = (const float*)d_in[4];
  const float* bmu = (const float*)d_in[5];
  const float* Wlv = (const float*)d_in[6];
  const float* blv = (const float*)d_in[7];
  float* out = (float*)d_out;

  const int N = in_sizes[0] / N_FEATS_IN;   // 100000
  const int E = in_sizes[1] / 2;            // 1600000

  char* ws = (char*)d_ws;
  size_t off = 0;
  auto alloc = [&](size_t bytes) -> void* {
    void* p = ws + off;
    off += (bytes + 255) & ~(size_t)255;
    return p;
  };
  __bf16* Yb  = (__bf16*)alloc((size_t)N * HID * 2);
  __bf16* Hb  = (__bf16*)alloc((size_t)N * HID * 2);
  float* dinv = (float*)alloc((size_t)N * 4);
  int*   deg  = (int*)alloc((size_t)N * 4);
  int*   ptr  = (int*)alloc((size_t)(N + 1) * 4);
  int*   cnt8 = (int*)alloc((size_t)NXCD * N * 4);
  int*   erank = (int*)alloc((size_t)E * 4);
  int2*  erec = (int2*)alloc((size_t)E * 8);
  __bf16* W1p = (__bf16*)alloc(32768 * 2);
  __bf16* Wcp = (__bf16*)alloc(16384 * 2);
  int*   bsum = (int*)alloc(256 * 4);
  (void)ws_size; (void)n_in; (void)out_size;

  hipMemsetAsync(cnt8, 0, (size_t)NXCD * N * 4, stream);

  int ge = (E + 255) / 256;
  int gn = (N + 255) / 256;
  int nb = (N + 256 * SITEMS - 1) / (256 * SITEMS);
  count_deg_kernel<<<ge, 256, 0, stream>>>(ei, E, N, cnt8, erank);
  combine_kernel<<<gn, 256, 0, stream>>>(cnt8, deg, dinv, N);
  scan_part_kernel<<<nb, 256, 0, stream>>>(deg, N, bsum);
  scan_bsum_kernel<<<1, 256, 0, stream>>>(bsum, nb);
  scan_final_kernel<<<nb, 256, 0, stream>>>(deg, N, bsum, ptr);
  fill_kernel<<<ge, 256, 0, stream>>>(ei, E, N, ptr, cnt8, erank, dinv, erec);
  pack_all_kernel<<<192, 256, 0, stream>>>(W1, Wmu, Wlv, W1p, Wcp);

  int g1 = (N + 127) / 128;                 // one 128-row tile per block
  gemm1_mfma<<<g1, 256, 0, stream>>>(X, W1p, Yb, N);
  agg_kernel<<<N, 64, 0, stream>>>(Yb, ptr, erec, dinv, b1, Hb, 1);  // H = relu(ÂY+b1)
  agg_kernel<<<N, 64, 0, stream>>>(Hb, ptr, erec, dinv, b1, Yb, 0);  // G = ÂH
  int ntiles2 = (N + 63) / 64;
  int g2 = ntiles2 < 768 ? ntiles2 : 768;
  gemm2_mfma<<<g2, 256, 0, stream>>>(Yb, Wcp, bmu, blv, out, N, ntiles2);
}

// Round 9
// 402.487 us; speedup vs baseline: 1.1977x; 1.1328x over previous
//
#include <hip/hip_runtime.h>
#include <hip/hip_bf16.h>
#include <cstdint>

#define N_FEATS_IN 256
#define HID 128
#define OUTF 64
#define NBMAX 400   // max buckets (N<=102400); N=100000 -> NB=391
#define BCAP 6144   // max edges staged in LDS per bucket (mean 4096, 30 sigma margin)
#define XS_STRIDE 264

typedef __bf16 bf16x8 __attribute__((ext_vector_type(8)));
typedef __bf16 bf16x4 __attribute__((ext_vector_type(4)));
typedef __bf16 bf16x2 __attribute__((ext_vector_type(2)));
typedef float f32x4 __attribute__((ext_vector_type(4)));

// ---- CSR build: LDS counting-sort by 256-node bucket --------------------
// Avoids per-edge global atomics entirely (gfx950 global atomic RMW writes
// through to HBM ~32B each — measured 56 MB WRITE for 1.6M atomics).

// K1: per-block LDS histogram over buckets; one global atomic per
// (block,bucket) reserves that block's range within the bucket.
__global__ __launch_bounds__(256) void bucket_count(const int* __restrict__ ei, int E,
    int CH, int NB, int* __restrict__ gbk, int* __restrict__ bbase) {
  __shared__ int cnt[NBMAX];
  const int t = threadIdx.x, blk = blockIdx.x;
  for (int i = t; i < NB; i += 256) cnt[i] = 0;
  __syncthreads();
  int base = blk * CH, lim = min(base + CH, E);
  for (int i = base + t; i < lim; i += 256) atomicAdd(&cnt[ei[E + i] >> 8], 1);
  __syncthreads();
  for (int i = t; i < NB; i += 256) {
    int b = (i + blk) % NB;  // stagger to spread atomic line contention
    int v = cnt[b];
    bbase[(size_t)blk * NB + b] = (v > 0) ? atomicAdd(&gbk[b], v) : 0;
  }
}

// K2: exclusive scan of NB bucket totals (NB <= 512)
__global__ __launch_bounds__(512) void bucket_scan(const int* __restrict__ gbk,
    int* __restrict__ gbkoff, int NB, int E) {
  __shared__ int ts[512];
  const int t = threadIdx.x;
  int v = (t < NB) ? gbk[t] : 0;
  ts[t] = v;
  __syncthreads();
  for (int off = 1; off < 512; off <<= 1) {
    int u = (t >= off) ? ts[t - off] : 0;
    __syncthreads();
    ts[t] += u;
    __syncthreads();
  }
  if (t < NB) gbkoff[t] = ts[t] - v;
  if (t == 0) gbkoff[NB] = E;
}

// K3: scatter edges into bucket-grouped array via LDS cursors (runs ~128B)
__global__ __launch_bounds__(256) void bucket_scatter(const int* __restrict__ ei, int E,
    int CH, int NB, const int* __restrict__ gbkoff, const int* __restrict__ bbase,
    int2* __restrict__ bucketed) {
  __shared__ int cur[NBMAX];
  const int t = threadIdx.x, blk = blockIdx.x;
  for (int i = t; i < NB; i += 256)
    cur[i] = gbkoff[i] + bbase[(size_t)blk * NB + i];
  __syncthreads();
  int base = blk * CH, lim = min(base + CH, E);
  for (int i = base + t; i < lim; i += 256) {
    int s = ei[i];
    int c = ei[E + i];
    int p = atomicAdd(&cur[c >> 8], 1);
    bucketed[p] = make_int2(s, c);
  }
}

// K4: per-bucket local CSR: LDS histogram (256 nodes) + LDS scan -> ptr,
// dinv, and in-bucket ordered csrc. ptr needs no global node scan:
// ptr[node] = gbkoff[bucket] + local_exclusive[node&255].
__global__ __launch_bounds__(256) void bucket_csr(const int2* __restrict__ bucketed,
    const int* __restrict__ gbkoff, int NB, int N, int E,
    float* __restrict__ dinv, int* __restrict__ ptr, int* __restrict__ csrc) {
  __shared__ int2 eb[BCAP];
  __shared__ int cnt[256], scn[256], cur[256];
  const int b = blockIdx.x, t = threadIdx.x;
  const int beg = gbkoff[b], end = gbkoff[b + 1];
  const int M = end - beg;
  cnt[t] = 0;
  __syncthreads();
  const bool inlds = (M <= BCAP);
  if (inlds) {
    for (int i = t; i < M; i += 256) {
      int2 r = bucketed[beg + i];
      eb[i] = r;
      atomicAdd(&cnt[r.y & 255], 1);
    }
  } else {
    for (int i = t; i < M; i += 256) atomicAdd(&cnt[bucketed[beg + i].y & 255], 1);
  }
  __syncthreads();
  const int c0 = cnt[t];
  scn[t] = c0;
  __syncthreads();
  for (int off = 1; off < 256; off <<= 1) {
    int u = (t >= off) ? scn[t - off] : 0;
    __syncthreads();
    scn[t] += u;
    __syncthreads();
  }
  const int excl = scn[t] - c0;
  const int node = b * 256 + t;
  if (node < N) {
    ptr[node] = beg + excl;
    dinv[node] = rsqrtf((float)(c0 + 1));  // +1 self-loop
  }
  if (b == NB - 1 && t == 0) ptr[N] = E;
  cur[t] = excl;
  __syncthreads();
  if (inlds) {
    for (int i = t; i < M; i += 256) {
      int2 r = eb[i];
      int slot = atomicAdd(&cur[r.y & 255], 1);
      csrc[beg + slot] = r.x;
    }
  } else {
    for (int i = t; i < M; i += 256) {
      int2 r = bucketed[beg + i];
      int slot = atomicAdd(&cur[r.y & 255], 1);
      csrc[beg + slot] = r.x;
    }
  }
}

// ---- weight repack into MFMA B-fragment order ---------------------------

__global__ __launch_bounds__(256) void pack_all_kernel(const float* __restrict__ W1,
    const float* __restrict__ Wmu, const float* __restrict__ Wlv,
    __bf16* __restrict__ W1p, __bf16* __restrict__ Wcp) {
  int idx = blockIdx.x * 256 + threadIdx.x;  // 32768 + 16384 = 49152
  if (idx < 32768) {
    int j = idx & 7, l = (idx >> 3) & 63, t = (idx >> 9) & 7, s = idx >> 12;
    int k = s * 32 + (l >> 4) * 8 + j;
    int n = t * 16 + (l & 15);
    W1p[idx] = (__bf16)W1[k * HID + n];
  } else if (idx < 49152) {
    int i2 = idx - 32768;
    int j = i2 & 7, l = (i2 >> 3) & 63, t = (i2 >> 9) & 7, s = i2 >> 12;
    int k = s * 32 + (l >> 4) * 8 + j;
    int g = t * 16 + (l & 15);
    float v = (g < OUTF) ? Wmu[k * OUTF + g] : Wlv[k * OUTF + (g - OUTF)];
    Wcp[i2] = (__bf16)v;
  }
}

// ---- GEMM1 (MFMA): Yb[N][128] = bf16( X[N][256] @ W1 ) ------------------
// Sequential X staging through LDS (R8: fixed the strided-stream DRAM
// thrash). B-frags from global (64 KB, L1-hot).

__global__ __launch_bounds__(256) void gemm1_mfma(const float* __restrict__ X,
    const __bf16* __restrict__ Wp, __bf16* __restrict__ Yb, int nrows) {
  __shared__ __bf16 xs[128 * XS_STRIDE];  // 66 KB
  const int tid = threadIdx.x;
  const int rowbase = blockIdx.x * 128;

#pragma unroll
  for (int i = 0; i < 32; ++i) {
    int idx = i * 256 + tid;
    int row = idx >> 6;
    int cc = idx & 63;
    int gr = min(rowbase + row, nrows - 1);
    float4 v = ((const float4*)(X + (size_t)gr * N_FEATS_IN))[cc];
    bf16x4 b;
    b[0] = (__bf16)v.x; b[1] = (__bf16)v.y; b[2] = (__bf16)v.z; b[3] = (__bf16)v.w;
    *(bf16x4*)(xs + row * XS_STRIDE + cc * 4) = b;
  }
  __syncthreads();

  const int lane = tid & 63;
  const int wave = tid >> 6;
  const int lm = lane & 15;
  const int q = lane >> 4;
  const bf16x8* wp = (const bf16x8*)Wp;

  f32x4 acc[2][8];
#pragma unroll
  for (int m = 0; m < 2; ++m)
#pragma unroll
    for (int t = 0; t < 8; ++t) acc[m][t] = (f32x4)0.f;

#pragma unroll
  for (int s = 0; s < 8; ++s) {
    bf16x8 a0 = *(const bf16x8*)(xs + (wave * 32 + lm) * XS_STRIDE + s * 32 + q * 8);
    bf16x8 a1 = *(const bf16x8*)(xs + (wave * 32 + 16 + lm) * XS_STRIDE + s * 32 + q * 8);
#pragma unroll
    for (int t = 0; t < 8; ++t) {
      bf16x8 b = wp[(s * 8 + t) * 64 + lane];
      acc[0][t] = __builtin_amdgcn_mfma_f32_16x16x32_bf16(a0, b, acc[0][t], 0, 0, 0);
      acc[1][t] = __builtin_amdgcn_mfma_f32_16x16x32_bf16(a1, b, acc[1][t], 0, 0, 0);
    }
  }
#pragma unroll
  for (int m = 0; m < 2; ++m) {
    int rb = rowbase + wave * 32 + m * 16 + q * 4;
#pragma unroll
    for (int t = 0; t < 8; ++t) {
#pragma unroll
      for (int r2 = 0; r2 < 4; ++r2) {
        int row = rb + r2;
        if (row < nrows) Yb[(size_t)row * HID + t * 16 + lm] = (__bf16)acc[m][t][r2];
      }
    }
  }
}

// ---- aggregation (bf16 in/out, f32 accumulate) --------------------------
// Fout[c] = d*( d*Fin[c] + sum_e dinv[src]*Fin[src] ), d = dinv[c].
// csrc stream is 4B/edge; dinv[src] is an L2-resident broadcast load.

__global__ __launch_bounds__(64) void agg_kernel(const __bf16* __restrict__ Fin,
    const int* __restrict__ ptr, const int* __restrict__ csrc,
    const float* __restrict__ dinv, const float* __restrict__ bias,
    __bf16* __restrict__ Fout, int do_relu) {
  const int c = blockIdx.x;
  const int t = threadIdx.x;
  const float d = dinv[c];
  bf16x2 sv = ((const bf16x2*)(Fin + (size_t)c * HID))[t];
  float ax = d * (float)sv[0];
  float ay = d * (float)sv[1];
  const int beg = ptr[c], end = ptr[c + 1];
  int e = beg;
  for (; e + 8 <= end; e += 8) {
    int r[8];
#pragma unroll
    for (int i = 0; i < 8; ++i) r[i] = csrc[e + i];
    float nr[8];
#pragma unroll
    for (int i = 0; i < 8; ++i) nr[i] = dinv[r[i]];
    bf16x2 v[8];
#pragma unroll
    for (int i = 0; i < 8; ++i) v[i] = ((const bf16x2*)(Fin + (size_t)r[i] * HID))[t];
#pragma unroll
    for (int i = 0; i < 8; ++i) {
      ax = fmaf(nr[i], (float)v[i][0], ax);
      ay = fmaf(nr[i], (float)v[i][1], ay);
    }
  }
  for (; e < end; ++e) {
    int r = csrc[e];
    float nr = dinv[r];
    bf16x2 v = ((const bf16x2*)(Fin + (size_t)r * HID))[t];
    ax = fmaf(nr, (float)v[0], ax);
    ay = fmaf(nr, (float)v[1], ay);
  }
  ax *= d;
  ay *= d;
  if (do_relu) {
    ax = fmaxf(ax + bias[2 * t], 0.f);
    ay = fmaxf(ay + bias[2 * t + 1], 0.f);
  }
  bf16x2 o;
  o[0] = (__bf16)ax;
  o[1] = (__bf16)ay;
  ((bf16x2*)(Fout + (size_t)c * HID))[t] = o;
}

// ---- GEMM2 (MFMA): [mu|lv] = Gb[N][128] @ Wc[128][128] + bias -----------

__global__ __launch_bounds__(256) void gemm2_mfma(const __bf16* __restrict__ Gb,
    const __bf16* __restrict__ Wp, const float* __restrict__ bmu,
    const float* __restrict__ blv, float* __restrict__ out, int nrows, int ntiles) {
  __shared__ __bf16 bs[16384];  // 32 KB: full Wc in B-frag order
  const int tid = threadIdx.x;
  {
    const float4* s4 = (const float4*)Wp;
    float4* d4 = (float4*)bs;
#pragma unroll
    for (int i = 0; i < 8; ++i) d4[tid + 256 * i] = s4[tid + 256 * i];
  }
  __syncthreads();
  const int lane = tid & 63;
  const int wave = tid >> 6;
  const int lm = lane & 15;
  const int q = lane >> 4;
  const bf16x8* bsv = (const bf16x8*)bs;

  float bv[8];
  size_t obase[8];
#pragma unroll
  for (int t = 0; t < 8; ++t) {
    int col = t * 16 + lm;
    bv[t] = (col < OUTF) ? bmu[col] : blv[col - OUTF];
    obase[t] = (col < OUTF) ? (size_t)col : ((size_t)nrows * OUTF + (col - OUTF));
  }

  for (int tile = blockIdx.x; tile < ntiles; tile += gridDim.x) {
    const int row0 = tile * 64 + wave * 16;
    const int r = min(row0 + lm, nrows - 1);
    const bf16x8* gp = (const bf16x8*)(Gb + (size_t)r * HID);

    bf16x8 xa[4];
#pragma unroll
    for (int s = 0; s < 4; ++s) xa[s] = gp[s * 4 + q];

    f32x4 acc[8];
#pragma unroll
    for (int t = 0; t < 8; ++t) acc[t] = (f32x4)0.f;

#pragma unroll
    for (int s = 0; s < 4; ++s) {
#pragma unroll
      for (int t = 0; t < 8; ++t)
        acc[t] = __builtin_amdgcn_mfma_f32_16x16x32_bf16(xa[s], bsv[(s * 8 + t) * 64 + lane],
                                                         acc[t], 0, 0, 0);
    }
#pragma unroll
    for (int t = 0; t < 8; ++t) {
#pragma unroll
      for (int r2 = 0; r2 < 4; ++r2) {
        int row = row0 + q * 4 + r2;
        if (row < nrows) out[obase[t] + (size_t)row * OUTF] = acc[t][r2] + bv[t];
      }
    }
  }
}

// ---- launch -------------------------------------------------------------

extern "C" void kernel_launch(void* const* d_in, const int* in_sizes, int n_in,
                              void* d_out, int out_size, void* d_ws, size_t ws_size,
                              hipStream_t stream) {
  const float* X   = (const float*)d_in[0];
  const int*   ei  = (const int*)d_in[1];
  const float* W1  = (const float*)d_in[2];
  const float* b1  = (const float*)d_in[3];
  const float* Wmu = (const float*)d_in[4];
  const float* bmu = (const float*)d_in[5];
  const float* Wlv = (const float*)d_in[6];
  const float* blv = (const float*)d_in[7];
  float* out = (float*)d_out;

  const int N = in_sizes[0] / N_FEATS_IN;   // 100000
  const int E = in_sizes[1] / 2;            // 1600000

  char* ws = (char*)d_ws;
  size_t off = 0;
  auto alloc = [&](size_t bytes) -> void* {
    void* p = ws + off;
    off += (bytes + 255) & ~(size_t)255;
    return p;
  };
  __bf16* Yb   = (__bf16*)alloc((size_t)N * HID * 2);  // gemm1 out; reused as G
  __bf16* Hb   = (__bf16*)alloc((size_t)N * HID * 2);  // relu(Â Y + b1)
  float* dinv  = (float*)alloc((size_t)N * 4);
  int*   ptr   = (int*)alloc((size_t)(N + 1) * 4);
  int2*  bucketed = (int2*)alloc((size_t)E * 8);
  int*   csrc  = (int*)alloc((size_t)E * 4);
  int*   gbk   = (int*)alloc((size_t)NBMAX * 4);
  int*   gbkoff = (int*)alloc((size_t)(NBMAX + 1) * 4);
  int*   bbase = (int*)alloc((size_t)256 * NBMAX * 4);
  __bf16* W1p  = (__bf16*)alloc(32768 * 2);
  __bf16* Wcp  = (__bf16*)alloc(16384 * 2);
  (void)ws_size; (void)n_in; (void)out_size;

  const int NB = (N + 255) >> 8;            // 391
  const int P = 256;
  const int CH = (E + P - 1) / P;           // 6250

  hipMemsetAsync(gbk, 0, (size_t)NB * 4, stream);
  bucket_count<<<P, 256, 0, stream>>>(ei, E, CH, NB, gbk, bbase);
  bucket_scan<<<1, 512, 0, stream>>>(gbk, gbkoff, NB, E);
  bucket_scatter<<<P, 256, 0, stream>>>(ei, E, CH, NB, gbkoff, bbase, bucketed);
  bucket_csr<<<NB, 256, 0, stream>>>(bucketed, gbkoff, NB, N, E, dinv, ptr, csrc);
  pack_all_kernel<<<192, 256, 0, stream>>>(W1, Wmu, Wlv, W1p, Wcp);

  int g1 = (N + 127) / 128;
  gemm1_mfma<<<g1, 256, 0, stream>>>(X, W1p, Yb, N);
  agg_kernel<<<N, 64, 0, stream>>>(Yb, ptr, csrc, dinv, b1, Hb, 1);  // H = relu(ÂY+b1)
  agg_kernel<<<N, 64, 0, stream>>>(Hb, ptr, csrc, dinv, b1, Yb, 0);  // G = ÂH
  int ntiles2 = (N + 63) / 64;
  int g2 = ntiles2 < 768 ? ntiles2 : 768;
  gemm2_mfma<<<g2, 256, 0, stream>>>(Yb, Wcp, bmu, blv, out, N, ntiles2);
}